// Round 9
// baseline (37.529 us; speedup 1.0000x reference)
//
#include <hip/hip_runtime.h>

// ClusteringLayer: q[n,k] = normalize_k( 1 / (1 + ||x_n - c_k||^2) )
// x: [65536,256] fp32, clusters: [256,256] fp32, out: [65536,256] fp32.
// R8: max-wave streaming. 1024-thr blocks (16 waves = CU max at 128 VGPR),
// grid 256 = 1 block/CU. Wave owns ONE 16-row tile: ld[16] and acc[16]
// never simultaneously live -> no spill. All 16 waves burst-issue X loads
// at t=0 (~256 KB/CU in flight) -> HBM queue never drains. B' (-2c, f16
// fragments) in 128 KB LDS; 1 barrier; wave-local row-norm; direct stores.

typedef _Float16 f16x8 __attribute__((ext_vector_type(8)));
typedef float    f32x4 __attribute__((ext_vector_type(4)));

#define DIM    256
#define NCLUST 256

// ---------------------------------------------------------------------------
// Pre-kernel: blocks 0..127 -> B' = (-2*clusters) as f16 fragments in ws
//             blocks 128..383 -> c2p1[j] = 1 + sum_d clusters[j][d]^2
// Fragment f = s*16 + t; lane l holds
// B'[col = t*16 + (l&15)][k = s*32 + (l>>4)*8 + v], v = 0..7.
// A uses the same (group,v)->k map, so any HW k-permutation cancels.
// ---------------------------------------------------------------------------
__global__ __launch_bounds__(64) void pre_kernel(const float* __restrict__ clusters,
                                                 _Float16* __restrict__ bfrag,
                                                 float* __restrict__ c2p1) {
    int b = blockIdx.x;
    int l = threadIdx.x;
    if (b < 128) {
        int s   = b >> 4;
        int t   = b & 15;
        int col = t * 16 + (l & 15);
        int k0  = s * 32 + (l >> 4) * 8;
        const f32x4* p = reinterpret_cast<const f32x4*>(clusters + col * DIM + k0);
        f32x4 a = p[0];
        f32x4 c = p[1];
        f16x8 h;
        h[0] = (_Float16)(-2.0f * a[0]); h[1] = (_Float16)(-2.0f * a[1]);
        h[2] = (_Float16)(-2.0f * a[2]); h[3] = (_Float16)(-2.0f * a[3]);
        h[4] = (_Float16)(-2.0f * c[0]); h[5] = (_Float16)(-2.0f * c[1]);
        h[6] = (_Float16)(-2.0f * c[2]); h[7] = (_Float16)(-2.0f * c[3]);
        reinterpret_cast<f16x8*>(bfrag)[b * 64 + l] = h;
    } else {
        int j = b - 128;
        const f32x4* p = reinterpret_cast<const f32x4*>(clusters + j * DIM);
        f32x4 v = p[l];
        float s = v[0] * v[0] + v[1] * v[1] + v[2] * v[2] + v[3] * v[3];
#pragma unroll
        for (int m = 32; m >= 1; m >>= 1) s += __shfl_xor(s, m, 64);
        if (l == 0) c2p1[j] = 1.0f + s;
    }
}

// ---------------------------------------------------------------------------
// Main kernel: 256 blocks x 1024 threads (16 waves, 1 block/CU).
// Wave w owns tile (blockIdx*16 + w): 16 rows x all 256 cols.
// acc = -2*x.c ; d = x2 + (1+c2) + acc ; q = rcp(d); wave-local row-norm.
// ---------------------------------------------------------------------------
__global__ __launch_bounds__(1024, 1) void cluster_kernel(const float* __restrict__ x,
                                                          const f32x4* __restrict__ bfrag,
                                                          const float* __restrict__ c2p1,
                                                          float* __restrict__ out) {
    __shared__ __align__(16) _Float16 Bs[65536];   // 128 KB: 128 frags x 1 KB

    const int tid  = threadIdx.x;
    const int lane = tid & 63;
    const int wave = tid >> 6;
    const int cl   = lane & 15;
    const int g    = lane >> 4;
    const int tile = blockIdx.x * 16 + wave;

    // ---- issue this wave's X loads first (HBM; 16 x 16B per lane) ----
    f32x4 ld[16];
    {
        const float* xr = x + (size_t)(tile * 16 + cl) * DIM + g * 8;
#pragma unroll
        for (int s = 0; s < 8; ++s) {
            ld[2 * s]     = *reinterpret_cast<const f32x4*>(xr + s * 32);
            ld[2 * s + 1] = *reinterpret_cast<const f32x4*>(xr + s * 32 + 4);
        }
    }

    // ---- stage B' fragments into LDS (L2-hot source, coalesced) ----
    {
        f32x4* dst = reinterpret_cast<f32x4*>(Bs);
#pragma unroll
        for (int i = 0; i < 8; ++i) {
            int idx = i * 1024 + tid;
            dst[idx] = bfrag[idx];
        }
    }
    __syncthreads();   // the only barrier

    // ---- build A fragments + x2 (frees ld) ----
    f16x8 af[8];
    float x2p = 0.0f;
#pragma unroll
    for (int s = 0; s < 8; ++s) {
        f32x4 a = ld[2 * s], b = ld[2 * s + 1];
        x2p += a[0]*a[0] + a[1]*a[1] + a[2]*a[2] + a[3]*a[3]
             + b[0]*b[0] + b[1]*b[1] + b[2]*b[2] + b[3]*b[3];
        af[s][0] = (_Float16)a[0]; af[s][1] = (_Float16)a[1];
        af[s][2] = (_Float16)a[2]; af[s][3] = (_Float16)a[3];
        af[s][4] = (_Float16)b[0]; af[s][5] = (_Float16)b[1];
        af[s][6] = (_Float16)b[2]; af[s][7] = (_Float16)b[3];
    }
    float x2full = x2p + __shfl_xor(x2p, 16, 64);
    x2full += __shfl_xor(x2full, 32, 64);      // x2 of row (tile*16 + cl)

    // ---- MFMA: 16 rows x 256 cols, B from LDS ----
    f32x4 acc[16];
#pragma unroll
    for (int t = 0; t < 16; ++t) {
        acc[t][0] = 0.f; acc[t][1] = 0.f; acc[t][2] = 0.f; acc[t][3] = 0.f;
    }
    const char* bsb = reinterpret_cast<const char*>(Bs) + lane * 16;
    __builtin_amdgcn_s_setprio(1);
#pragma unroll
    for (int s = 0; s < 8; ++s) {
#pragma unroll
        for (int t = 0; t < 16; ++t) {
            f16x8 bf = *reinterpret_cast<const f16x8*>(bsb + (s * 16 + t) * 1024);
            acc[t] = __builtin_amdgcn_mfma_f32_16x16x32_f16(af[s], bf, acc[t], 0, 0, 0);
        }
    }
    __builtin_amdgcn_s_setprio(0);

    // ---- c2p1 for this lane's columns (L2-hot; loaded late on purpose) ----
    float c2v[16];
#pragma unroll
    for (int t = 0; t < 16; ++t) c2v[t] = c2p1[t * 16 + cl];

    // ---- epilogue: d = x2 + (1+c2) + acc ; q = rcp(d); row-normalize ----
    // C/D layout: col = lane&15, row = (lane>>4)*4 + reg.
    float x2j[4];
#pragma unroll
    for (int j = 0; j < 4; ++j) x2j[j] = __shfl(x2full, g * 4 + j, 64);

    float rsum[4] = {0.f, 0.f, 0.f, 0.f};
#pragma unroll
    for (int t = 0; t < 16; ++t) {
#pragma unroll
        for (int j = 0; j < 4; ++j) {
            float d = x2j[j] + c2v[t] + acc[t][j];
            float q = __builtin_amdgcn_rcpf(d);
            acc[t][j] = q;
            rsum[j] += q;
        }
    }
#pragma unroll
    for (int j = 0; j < 4; ++j) {
        float v = rsum[j];
        v += __shfl_xor(v, 1, 64); v += __shfl_xor(v, 2, 64);
        v += __shfl_xor(v, 4, 64); v += __shfl_xor(v, 8, 64);
        rsum[j] = __builtin_amdgcn_rcpf(v);
    }
    float* ob = out + (size_t)(tile * 16) * NCLUST;
#pragma unroll
    for (int t = 0; t < 16; ++t)
#pragma unroll
        for (int j = 0; j < 4; ++j)
            ob[(g * 4 + j) * NCLUST + t * 16 + cl] = acc[t][j] * rsum[j];
}

extern "C" void kernel_launch(void* const* d_in, const int* in_sizes, int n_in,
                              void* d_out, int out_size, void* d_ws, size_t ws_size,
                              hipStream_t stream) {
    const float* x        = (const float*)d_in[0];
    const float* clusters = (const float*)d_in[1];
    float* out = (float*)d_out;

    _Float16* bfrag = (_Float16*)d_ws;                       // 128*64*16B = 128 KB
    float*    c2p1  = (float*)((char*)d_ws + 128 * 64 * 16); // 1 KB

    pre_kernel<<<384, 64, 0, stream>>>(clusters, bfrag, c2p1);

    int nrows = in_sizes[0] / DIM;              // 65536
    int grid  = nrows / (16 * 16);              // 256
    cluster_kernel<<<grid, 1024, 0, stream>>>(x, (const f32x4*)bfrag, c2p1, out);
}